// Round 3
// baseline (2919.484 us; speedup 1.0000x reference)
//
#include <hip/hip_runtime.h>
#include <stdint.h>

// Problem dims
#define BATCH 128
#define SEQ   512
#define DIN   256
#define HID   512
#define NWG   256    // 4 groups x 64 WGs; 1 WG/CU
#define TPB   512    // 8 waves = (m 0..1) x (kq 0..3)
#define NSLOT 513
#define OUTD  1275
#define HSLOT (BATCH * HID)   // shorts per h slot (128 KB)

// workspace layout
#define WS_FLAGS 0                         // 4 groups x 64 u32
#define WS_H0    4096                      // 4 x 128KB h0 ring (depth 4)
#define WS_H1    (4096 + 524288)           // 2 x 128KB h1 ring
#define WS_H1FIN (4096 + 524288 + 262144)  // 256KB f32
#define WS_XB    (WS_H1FIN + 262144)       // 32MB
#define WS_MSET  (4096 + 524288 + 262144)  // memset covers flags+h0+h1

typedef __attribute__((ext_vector_type(8))) short bf16x8;
typedef __attribute__((ext_vector_type(4))) unsigned int uint4v;
typedef __attribute__((ext_vector_type(4))) float f32x4;

static __device__ __forceinline__ unsigned short f2bf(float f) {
  unsigned int u = __builtin_bit_cast(unsigned int, f);
  u += 0x7FFFu + ((u >> 16) & 1u);  // RNE
  return (unsigned short)(u >> 16);
}
static __device__ __forceinline__ float sigmoidf_fast(float v) {
  float e = __expf(-fabsf(v));
  float s = 1.0f / (1.0f + e);
  return v >= 0.0f ? s : 1.0f - s;
}
static __device__ __forceinline__ float tanhf_fast(float v) {
  float e = __expf(-2.0f * fabsf(v));
  float t = (1.0f - e) / (1.0f + e);
  return v >= 0.0f ? t : -t;
}

// Fine-grained (coherence-point) ops: sc0 sc1 bypass L1+L2 — no cache
// maintenance anywhere in the steady-state loop.
static __device__ __forceinline__ void ldg_nc(bf16x8& d, const unsigned short* p) {
  asm volatile("global_load_dwordx4 %0, %1, off sc0 sc1" : "=v"(d) : "v"(p));
}
static __device__ __forceinline__ void ldg_nc_dw(unsigned int& d, const unsigned int* p) {
  asm volatile("global_load_dword %0, %1, off sc0 sc1" : "=v"(d) : "v"(p));
}
static __device__ __forceinline__ void stg_nc16(unsigned short* p, uint4v v) {
  asm volatile("global_store_dwordx4 %0, %1, off sc0 sc1" :: "v"(p), "v"(v) : "memory");
}
static __device__ __forceinline__ void stg_nc4(unsigned int* p, unsigned int v) {
  asm volatile("global_store_dword %0, %1, off sc0 sc1" :: "v"(p), "v"(v) : "memory");
}
#define WAIT_TIE1(v) asm volatile("s_waitcnt vmcnt(0)" : "+v"(v) :: "memory")
#define WAIT_TIE4(A)                                                          \
  asm volatile("s_waitcnt vmcnt(0)"                                           \
               : "+v"((A)[0]), "+v"((A)[1]), "+v"((A)[2]), "+v"((A)[3])       \
               :: "memory")
#define WAIT_TIE6(A)                                                          \
  asm volatile("s_waitcnt vmcnt(0)"                                           \
               : "+v"((A)[0]), "+v"((A)[1]), "+v"((A)[2]), "+v"((A)[3]),      \
                 "+v"((A)[4]), "+v"((A)[5]) :: "memory")
#define WAIT_TIE8(A)                                                          \
  asm volatile("s_waitcnt vmcnt(0)"                                           \
               : "+v"((A)[0]), "+v"((A)[1]), "+v"((A)[2]), "+v"((A)[3]),      \
                 "+v"((A)[4]), "+v"((A)[5]), "+v"((A)[6]), "+v"((A)[7])       \
               :: "memory")

// Poll 32 flags (lanes 0..31 own one, 32..63 duplicate) until all >= thr;
// returns min (sticky horizon lets callers skip future polls).
static __device__ __forceinline__ int poll_min32(const unsigned int* base, int thr) {
  const unsigned int* fp = base + (threadIdx.x & 31);
  for (;;) {
    unsigned int v;
    ldg_nc_dw(v, fp);
    WAIT_TIE1(v);
    if (__ballot(v >= (unsigned int)thr) == ~0ull) {
      int mn = (int)v;
#pragma unroll
      for (int o = 1; o < 64; o <<= 1) {
        int t = __shfl_xor(mn, o, 64);
        mn = t < mn ? t : mn;
      }
      return mn;
    }
    __builtin_amdgcn_s_sleep(1);
  }
}
// Poll all 64 flags (one per lane) until all >= thr; returns min.
static __device__ __forceinline__ int poll_min64(const unsigned int* base, int thr) {
  const unsigned int* fp = base + (threadIdx.x & 63);
  for (;;) {
    unsigned int v;
    ldg_nc_dw(v, fp);
    WAIT_TIE1(v);
    if (__ballot(v >= (unsigned int)thr) == ~0ull) {
      int mn = (int)v;
#pragma unroll
      for (int o = 1; o < 64; o <<= 1) {
        int t = __shfl_xor(mn, o, 64);
        mn = t < mn ? t : mn;
      }
      return mn;
    }
    __builtin_amdgcn_s_sleep(1);
  }
}

// x -> bf16 MFMA-fragment order: xb[(((p*8+mi)*8+kt)*64+lane)*8]
__global__ __launch_bounds__(256) void xprep(const float* __restrict__ x,
                                             unsigned short* __restrict__ xb) {
  int p = blockIdx.x;
  int lane = threadIdx.x & 63;
  int g4 = threadIdx.x >> 6;
  int c15 = lane & 15, q = lane >> 4;
  for (int g = 0; g < 16; ++g) {
    int idx = g * 4 + g4;  // (mi,kt)
    int mi = idx >> 3, kt = idx & 7;
    int row = mi * 16 + c15;
    const float* src = x + ((size_t)row * SEQ + p) * DIN + kt * 32 + q * 8;
    f32x4 a = *(const f32x4*)src;
    f32x4 b = *(const f32x4*)(src + 4);
    bf16x8 v;
    v[0] = (short)f2bf(a[0]); v[1] = (short)f2bf(a[1]);
    v[2] = (short)f2bf(a[2]); v[3] = (short)f2bf(a[3]);
    v[4] = (short)f2bf(b[0]); v[5] = (short)f2bf(b[1]);
    v[6] = (short)f2bf(b[2]); v[7] = (short)f2bf(b[3]);
    *(bf16x8*)&xb[((((size_t)p * 8 + mi) * 8 + kt) * 64 + lane) * 8] = v;
  }
}

// Persistent 2-layer LSTM, batch-split. 4 independent groups x 32 batch rows;
// group = 64 WGs (32 L0 + 32 L1), WG owns 16 units (64 gate-cols). 8 waves =
// (M-tile m, K-quarter kq): partial-K MFMA into f32 partials, LDS-reduced.
// DECOUPLED layers: h0 fabric ring depth 4, L0 polls only L0 flags (its own
// recurrence) and may run up to 3 slots ahead; a sticky ring-guard (L1 flags
// >= p-2) protects h0(p-4) from overwrite. L1 polls all 64 flags >= p (its
// h0(p-1) and h1(p-1) inputs) — L0's flag is normally already there, so the
// steady-state rate is max(L0 chain, L1 chain) instead of their sum.
template <bool USE_XB>
__global__ __launch_bounds__(TPB, 1) void lstm_persistent(
    const float* __restrict__ x, const unsigned short* __restrict__ xb,
    const float* __restrict__ W0, const float* __restrict__ b0,
    const float* __restrict__ W1, const float* __restrict__ b1,
    unsigned int* __restrict__ flags, unsigned short* __restrict__ h0buf,
    unsigned short* __restrict__ h1buf, float* __restrict__ h1fin)
{
  __shared__ unsigned short sWf[4 * 32 * 64 * 8];  // 128 KB B-frags [ct][kt][lane][8]
  __shared__ float red[4 * 32 * 33];               // 16.9 KB padded partials
  __shared__ unsigned short stage[32 * 16];        // 1 KB h stage

  const int tid  = threadIdx.x;
  const int wgid = blockIdx.x;
  const int g    = wgid >> 6;          // group 0..3 (batch rows 32g..32g+31)
  const int r    = wgid & 63;          // role in group
  const bool isA = (r < 32);
  const int unit0 = (isA ? r : r - 32) << 4;  // 16 units per WG
  const int lane = tid & 63;
  const int wv   = tid >> 6;
  const int m    = wv & 1;             // M-tile within group (16 rows)
  const int kq   = wv >> 1;            // K-quarter 0..3
  const int c15  = lane & 15;
  const int q    = lane >> 4;
  const int miG  = g * 2 + m;          // global M-tile
  const int KT   = isA ? 24 : 32;

  // ---- one-time: weights -> LDS fragment layout; col c = u_local*4 + gate ----
  {
    const float* W = isA ? W0 : W1;
    for (int f = tid; f < 4 * KT * 64; f += TPB) {
      int ct = f / (KT * 64);
      int rem = f - ct * (KT * 64);
      int kt = rem >> 6, ln = rem & 63;
      int qq = ln >> 4, cc = ln & 15;
      int u_local = ct * 4 + (cc >> 2);
      int gate = cc & 3;
      int gcol = gate * HID + unit0 + u_local;
      int kbase = kt * 32 + qq * 8;
      bf16x8 v;
#pragma unroll
      for (int j = 0; j < 8; ++j)
        v[j] = (short)f2bf(W[(size_t)(kbase + j) * 2048 + gcol]);
      *(bf16x8*)&sWf[(size_t)f * 8] = v;
    }
  }

  // gate-thread state (tid<256): thread = (row grow_, unit gu) x 2 chunks
  const int grow_ = tid >> 3, gu = tid & 7;
  float bias_c[2][4];
  float cst[2] = {0.f, 0.f};
  if (tid < 256) {
    const float* bv = isA ? b0 : b1;
#pragma unroll
    for (int ch = 0; ch < 2; ++ch)
#pragma unroll
      for (int gt = 0; gt < 4; ++gt)
        bias_c[ch][gt] = bv[gt * HID + unit0 + ch * 8 + gu];
  }
  __syncthreads();

  unsigned int* myflags = flags + g * 64;

#define BFRAG(ct, kt) (*(const bf16x8*)&sWf[((((ct) * KT + (kt)) << 6) + lane) << 3])

  int selfSeen = 0, bothSeen = 0, ringSeen = 0;  // sticky poll horizons

  for (int p = 0; p < NSLOT; ++p) {
    // h0 ring depth 4: slot s lives at idx s&3. Readers (L0 and L1, both at
    // their slot p) consume h0(p-1) at idx (p+3)&3; writer stores at p&3.
    const unsigned short* h0rd = h0buf + (size_t)((p + 3) & 3) * HSLOT;
    unsigned short* h0wr       = h0buf + (size_t)(p & 3) * HSLOT;
    const unsigned short* h1rd = h1buf + (size_t)(p & 1) * HSLOT;
    unsigned short* h1wr       = h1buf + (size_t)((p + 1) & 1) * HSLOT;
    const bool active = isA ? (p < SEQ) : (p >= 1);

    f32x4 acc[4];
#pragma unroll
    for (int ct = 0; ct < 4; ++ct) acc[ct] = (f32x4){0.f, 0.f, 0.f, 0.f};

    // ---- pre-poll: L0 x-part (kt<8 of my K-quarter), cached loads ----
    if (isA && active) {
      int ktlo = kq * 6, kthi = ktlo + 6;
      for (int kt = ktlo; kt < kthi && kt < 8; ++kt) {
        bf16x8 ax;
        if (USE_XB) {
          ax = *(const bf16x8*)&xb[((((size_t)p * 8 + miG) * 8 + kt) * 64 + lane) * 8];
        } else {
          const float* xp0 = x + (((size_t)(miG * 16 + c15)) * SEQ + p) * DIN + kt * 32 + q * 8;
          f32x4 a = *(const f32x4*)xp0;
          f32x4 b = *(const f32x4*)(xp0 + 4);
          ax[0] = (short)f2bf(a[0]); ax[1] = (short)f2bf(a[1]);
          ax[2] = (short)f2bf(a[2]); ax[3] = (short)f2bf(a[3]);
          ax[4] = (short)f2bf(b[0]); ax[5] = (short)f2bf(b[1]);
          ax[6] = (short)f2bf(b[2]); ax[7] = (short)f2bf(b[3]);
        }
#pragma unroll
        for (int ct = 0; ct < 4; ++ct)
          acc[ct] = __builtin_amdgcn_mfma_f32_16x16x32_bf16(ax, BFRAG(ct, kt), acc[ct], 0, 0, 0);
      }
    }

    // ---- dependency wait (wave0, ballot-poll, sticky) ----
    if (wv == 0 && p > 0) {
      if (isA) {
        if (selfSeen < p) selfSeen = poll_min32(myflags, p);          // L0 flags only
      } else {
        if (bothSeen < p) bothSeen = poll_min64(myflags, p);          // h0 + h1 deps
      }
    }
    __syncthreads();

    // ---- dependent K-part: fine-grained h loads, partial-K MFMA ----
    if (active) {
      if (isA) {
        if (kq == 1) {         // kt 8..11 -> h0 frag 0..3
          bf16x8 ah[4];
#pragma unroll
          for (int i = 0; i < 4; ++i)
            ldg_nc(ah[i], h0rd + ((size_t)(miG * 16 + i) * 64 + lane) * 8);
          WAIT_TIE4(ah);
#pragma unroll
          for (int i = 0; i < 4; ++i)
#pragma unroll
            for (int ct = 0; ct < 4; ++ct)
              acc[ct] = __builtin_amdgcn_mfma_f32_16x16x32_bf16(ah[i], BFRAG(ct, 8 + i), acc[ct], 0, 0, 0);
        } else if (kq >= 2) {  // kt 12..17 / 18..23 -> h0 frag 4..9 / 10..15
          bf16x8 ah[6];
          int kt0 = kq * 6;
#pragma unroll
          for (int i = 0; i < 6; ++i)
            ldg_nc(ah[i], h0rd + ((size_t)(miG * 16 + (kt0 - 8 + i)) * 64 + lane) * 8);
          WAIT_TIE6(ah);
#pragma unroll
          for (int i = 0; i < 6; ++i)
#pragma unroll
            for (int ct = 0; ct < 4; ++ct)
              acc[ct] = __builtin_amdgcn_mfma_f32_16x16x32_bf16(ah[i], BFRAG(ct, kt0 + i), acc[ct], 0, 0, 0);
        }
      } else {
        bf16x8 ah[8];
        const unsigned short* src = (kq < 2) ? h0rd : h1rd;
        int ktf0 = (kq < 2) ? kq * 8 : (kq - 2) * 8;
#pragma unroll
        for (int i = 0; i < 8; ++i)
          ldg_nc(ah[i], src + ((size_t)(miG * 16 + ktf0 + i) * 64 + lane) * 8);
        WAIT_TIE8(ah);
#pragma unroll
        for (int i = 0; i < 8; ++i)
#pragma unroll
          for (int ct = 0; ct < 4; ++ct)
            acc[ct] = __builtin_amdgcn_mfma_f32_16x16x32_bf16(ah[i], BFRAG(ct, kq * 8 + i), acc[ct], 0, 0, 0);
      }
    }

    // ---- cross-wave K-reduce + gates, 2 chunks of 32 cols (8 units) ----
#pragma unroll
    for (int ch = 0; ch < 2; ++ch) {
      __syncthreads();
      if (active) {
        int lrow = m * 16 + q * 4;
#pragma unroll
        for (int t = 0; t < 2; ++t)
#pragma unroll
          for (int rr = 0; rr < 4; ++rr)
            red[(kq * 32 + lrow + rr) * 33 + t * 16 + c15] = acc[ch * 2 + t][rr];
      }
      __syncthreads();
      if (active && tid < 256) {
        float z[4];
#pragma unroll
        for (int gt = 0; gt < 4; ++gt) {
          float s = bias_c[ch][gt];
          int cidx = gu * 4 + gt;
#pragma unroll
          for (int k2 = 0; k2 < 4; ++k2)
            s += red[(k2 * 32 + grow_) * 33 + cidx];
          z[gt] = s;
        }
        float cn = sigmoidf_fast(z[1]) * cst[ch] + sigmoidf_fast(z[0]) * tanhf_fast(z[2]);
        cst[ch] = cn;
        float hn = sigmoidf_fast(z[3]) * tanhf_fast(cn);
        stage[grow_ * 16 + ch * 8 + gu] = f2bf(hn);
        if (!isA && p == NSLOT - 1)
          h1fin[(size_t)(g * 32 + grow_) * HID + unit0 + ch * 8 + gu] = hn;
      }
    }
    __syncthreads();

    // ---- wave0: publish (frag layout, sc0sc1) + drain + flag ----
    if (wv == 0) {
      // ring guard: before overwriting h0(p-4) at idx p&3, ensure L1 finished
      // slot p-3 (the reader of h0(p-4)) i.e. L1 flags >= p-2. Sticky;
      // only blocks if L0 runs >3 slots ahead.
      if (isA && active && p > 3 && ringSeen < p - 2)
        ringSeen = poll_min32(myflags + 32, p - 2);
      if (active && tid < 64) {
        int row = tid >> 1, qq2 = tid & 1;
        uint4v v = *(const uint4v*)&stage[row * 16 + qq2 * 8];
        int mi = g * 2 + (row >> 4), r15 = row & 15;
        int ktu = unit0 >> 5;
        int qu = ((unit0 & 31) >> 3) + qq2;
        unsigned short* dst = (isA ? h0wr : h1wr) +
            ((size_t)(mi * 16 + ktu) * 64 + qu * 16 + r15) * 8;
        stg_nc16(dst, v);
      }
      asm volatile("s_waitcnt vmcnt(0)" ::: "memory");  // stores acked at fabric
      if (tid == 0) stg_nc4(myflags + r, (unsigned int)(p + 1));
    }
    // no trailing barrier: next slot's post-poll __syncthreads rejoins waves
  }
#undef BFRAG
}

__global__ __launch_bounds__(256) void proj_kernel(
    const float* __restrict__ h1, const float* __restrict__ Wp,
    const float* __restrict__ bp, float* __restrict__ out)
{
  int o = blockIdx.x * 256 + threadIdx.x;
  int b = blockIdx.y;
  if (o >= OUTD) return;
  const float* hr = h1 + (size_t)b * HID;
  float acc = bp[o];
#pragma unroll 8
  for (int k = 0; k < HID; ++k)
    acc = fmaf(hr[k], Wp[(size_t)k * OUTD + o], acc);
  out[(size_t)b * OUTD + o] = acc;
}

extern "C" void kernel_launch(void* const* d_in, const int* in_sizes, int n_in,
                              void* d_out, int out_size, void* d_ws, size_t ws_size,
                              hipStream_t stream) {
  const float* x  = (const float*)d_in[0];
  const float* W0 = (const float*)d_in[1];
  const float* b0 = (const float*)d_in[2];
  const float* W1 = (const float*)d_in[3];
  const float* b1 = (const float*)d_in[4];
  const float* Wp = (const float*)d_in[5];
  const float* bp = (const float*)d_in[6];
  float* out = (float*)d_out;

  char* ws = (char*)d_ws;
  unsigned int* flags = (unsigned int*)(ws + WS_FLAGS);  // 4 groups x 64 u32
  unsigned short* h0b = (unsigned short*)(ws + WS_H0);   // 512 KB (4 slots)
  unsigned short* h1b = (unsigned short*)(ws + WS_H1);   // 256 KB (2 slots)
  float* h1fin        = (float*)(ws + WS_H1FIN);         // 256 KB
  unsigned short* xbp = (unsigned short*)(ws + WS_XB);   // 32 MB
  const size_t need_xb = (size_t)WS_XB + (size_t)SEQ * BATCH * DIN * 2;
  const bool use_xb = (ws_size >= need_xb);

  hipMemsetAsync(d_ws, 0, WS_MSET, stream);
  if (use_xb) {
    hipLaunchKernelGGL(xprep, dim3(SEQ), dim3(256), 0, stream, x, xbp);
    hipLaunchKernelGGL(lstm_persistent<true>, dim3(NWG), dim3(TPB), 0, stream,
                       x, xbp, W0, b0, W1, b1, flags, h0b, h1b, h1fin);
  } else {
    hipLaunchKernelGGL(lstm_persistent<false>, dim3(NWG), dim3(TPB), 0, stream,
                       x, xbp, W0, b0, W1, b1, flags, h0b, h1b, h1fin);
  }
  hipLaunchKernelGGL(proj_kernel, dim3((OUTD + 255) / 256, BATCH), dim3(256), 0, stream,
                     h1fin, Wp, bp, out);
}